// Round 1
// baseline (1472.886 us; speedup 1.0000x reference)
//
#include <hip/hip_runtime.h>

// ---------------- problem constants ----------------
#define HHEADS 16
#define R1 4
#define R2 8
#define HD 64
#define CDIM 1024
#define NSEQ 2048
#define BATCH 2
#define NPROJ 1408            // 64 q1 + 64 k1 + 128 q2 + 128 k2 + 1024 v
#define MROWS (BATCH * NSEQ)  // 4096
#define SCALE 0.17677669529663687f  // (R1*R2)^-0.5

typedef __attribute__((ext_vector_type(8))) short bf16x8;
typedef __attribute__((ext_vector_type(4))) float f32x4;

// ---------------- bf16 helpers (raw ushort representation) ----------------
__device__ __forceinline__ float bflo(unsigned u) {            // low 16 bits -> f32
  return __uint_as_float(u << 16);
}
__device__ __forceinline__ float bfhi(unsigned u) {            // high 16 bits -> f32
  return __uint_as_float(u & 0xffff0000u);
}
__device__ __forceinline__ unsigned short f2bfr(float f) {     // f32 -> bf16 RNE
  unsigned u = __float_as_uint(f);
  u += 0x7fffu + ((u >> 16) & 1u);
  return (unsigned short)(u >> 16);
}

// ---------------- f32 -> bf16 conversion (vectorized) ----------------
__global__ void cvt_kernel(const float* __restrict__ src,
                           unsigned short* __restrict__ dst, int nvec) {
  for (int i = blockIdx.x * blockDim.x + threadIdx.x; i < nvec;
       i += gridDim.x * blockDim.x) {
    const float4 v = ((const float4*)src)[i];
    ushort4 o;
    o.x = f2bfr(v.x);
    o.y = f2bfr(v.y);
    o.z = f2bfr(v.z);
    o.w = f2bfr(v.w);
    ((ushort4*)dst)[i] = o;
  }
}

// ---------------- async global->LDS (16B per lane) ----------------
__device__ __forceinline__ void gld_lds16(const void* g, void* l) {
  __builtin_amdgcn_global_load_lds(
      (const __attribute__((address_space(1))) void*)g,
      (__attribute__((address_space(3))) void*)l, 16, 0, 0);
}

// ---------------- bf16 GEMM: C[M][N] = A[M][K] * Bw[N][K]^T ----------------
// 128x128 tile, BK=32, 256 threads = 4 waves (2x2), 16x16x32 MFMA.
// OUTMODE 0: bf16 output (Cb). OUTMODE 1: f32 output + bias (Cf).
template <int OUTMODE>
__global__ __launch_bounds__(256) void gemm_bt(
    const unsigned short* __restrict__ A, const unsigned short* __restrict__ Bw,
    unsigned short* __restrict__ Cb, float* __restrict__ Cf,
    const float* __restrict__ bias, int M, int N, int K) {
  __shared__ unsigned short As[128 * 32];
  __shared__ unsigned short Bs[128 * 32];
  const int tid = threadIdx.x;
  const long brow = (long)blockIdx.y * 128;
  const long bcol = (long)blockIdx.x * 128;
  const int w = tid >> 6, lane = tid & 63;
  const int wr = w >> 1, wc = w & 1;
  const int lr = lane & 15, kg = lane >> 4;

  f32x4 acc[4][4];
#pragma unroll
  for (int m = 0; m < 4; ++m)
#pragma unroll
    for (int n = 0; n < 4; ++n) acc[m][n] = (f32x4){0.f, 0.f, 0.f, 0.f};

  // staging geometry: each thread moves 16B per issue; 2 issues per operand
  const int off0 = tid * 16;      // byte offset within a 4KB half-tile
  const int row0 = off0 >> 6;     // 0..63 (64B = one 32-elem bf16 row)
  const int kel0 = (off0 & 63) >> 1;  // element offset within row (0,8,16,24)

  const int nk = K >> 5;
  for (int kt = 0; kt < nk; ++kt) {
    const long kbase = (long)kt * 32 + kel0;
    gld_lds16(A + (brow + row0) * K + kbase, (char*)As + off0);
    gld_lds16(A + (brow + 64 + row0) * K + kbase, (char*)As + 4096 + off0);
    gld_lds16(Bw + (bcol + row0) * K + kbase, (char*)Bs + off0);
    gld_lds16(Bw + (bcol + 64 + row0) * K + kbase, (char*)Bs + 4096 + off0);
    __syncthreads();  // drains vmcnt (global_load_lds) + barrier

    bf16x8 af[4], bfg[4];
#pragma unroll
    for (int m = 0; m < 4; ++m)
      af[m] = *(const bf16x8*)(As + (wr * 64 + m * 16 + lr) * 32 + kg * 8);
#pragma unroll
    for (int n = 0; n < 4; ++n)
      bfg[n] = *(const bf16x8*)(Bs + (wc * 64 + n * 16 + lr) * 32 + kg * 8);
#pragma unroll
    for (int m = 0; m < 4; ++m)
#pragma unroll
      for (int n = 0; n < 4; ++n)
        acc[m][n] = __builtin_amdgcn_mfma_f32_16x16x32_bf16(af[m], bfg[n],
                                                            acc[m][n], 0, 0, 0);
    __syncthreads();
  }

  // epilogue; C/D layout: col = lane&15, row = (lane>>4)*4 + i
#pragma unroll
  for (int m = 0; m < 4; ++m) {
#pragma unroll
    for (int i = 0; i < 4; ++i) {
      const long r = brow + wr * 64 + m * 16 + kg * 4 + i;
#pragma unroll
      for (int n = 0; n < 4; ++n) {
        const long c = bcol + wc * 64 + n * 16 + lr;
        const float v = acc[m][n][i];
        if (OUTMODE == 1) {
          Cf[r * N + c] = v + bias[c];
        } else {
          Cb[r * N + c] = f2bfr(v);
        }
      }
    }
  }
}

// ---------------- scalar causal attention (thread-per-query, d-split=2) ----
// proj row layout (per token): [q1: 0..63][k1: 64..127][q2: 128..255]
//                              [k2: 256..383][v: 384..1407]
// Key insight: all lanes of a wave walk the same key row m in lockstep,
// so k1/k2/v loads are wave-broadcast (L1-served). VALU-bound.
__global__ __launch_bounds__(256) void attn_scalar(
    const unsigned short* __restrict__ proj, unsigned short* __restrict__ ao) {
  const int tid = threadIdx.x;
  const int qloc = tid & 127;
  const int dh = tid >> 7;  // 0/1: which 32-dim half of the head
  const int blk = blockIdx.x;
  const int qb = blk & 15;
  const int bh = blk >> 4;
  const int h = bh & (HHEADS - 1);
  const int b = bh >> 4;
  const int n = qb * 128 + qloc;  // query index

  const unsigned short* base = proj + (size_t)b * NSEQ * NPROJ;
  const unsigned short* qrow = base + (size_t)n * NPROJ;

  float q1[4], q2[8];
  {
    const uint2 a = *(const uint2*)(qrow + h * 4);
    q1[0] = bflo(a.x); q1[1] = bfhi(a.x);
    q1[2] = bflo(a.y); q1[3] = bfhi(a.y);
    const uint4 c = *(const uint4*)(qrow + 128 + h * 8);
    q2[0] = bflo(c.x); q2[1] = bfhi(c.x);
    q2[2] = bflo(c.y); q2[3] = bfhi(c.y);
    q2[4] = bflo(c.z); q2[5] = bfhi(c.z);
    q2[6] = bflo(c.w); q2[7] = bfhi(c.w);
  }

  float acc[32];
#pragma unroll
  for (int j = 0; j < 32; ++j) acc[j] = 0.f;
  float mrun = -1e30f, lrun = 0.f;

  const int k1c = 64 + h * 4;
  const int k2c = 256 + h * 8;
  const int vc = 384 + h * 64 + dh * 32;

  for (int m = 0; m <= n; ++m) {
    const unsigned short* kr = base + (size_t)m * NPROJ;
    const uint2 kk1 = *(const uint2*)(kr + k1c);
    const uint4 kk2 = *(const uint4*)(kr + k2c);
    const float a1 = q1[0] * bflo(kk1.x) + q1[1] * bfhi(kk1.x) +
                     q1[2] * bflo(kk1.y) + q1[3] * bfhi(kk1.y);
    const float a2 = q2[0] * bflo(kk2.x) + q2[1] * bfhi(kk2.x) +
                     q2[2] * bflo(kk2.y) + q2[3] * bfhi(kk2.y) +
                     q2[4] * bflo(kk2.z) + q2[5] * bfhi(kk2.z) +
                     q2[6] * bflo(kk2.w) + q2[7] * bfhi(kk2.w);
    const float s = a1 * a2 * SCALE;
    float p, corr;
    if (s <= mrun) {
      p = __expf(s - mrun);
      corr = 1.f;
    } else {
      corr = __expf(mrun - s);  // first iter: exp(-huge) == 0
      p = 1.f;
      mrun = s;
    }
    lrun = lrun * corr + p;
    const uint4* vp = (const uint4*)(kr + vc);
#pragma unroll
    for (int j = 0; j < 4; ++j) {
      const uint4 pk = vp[j];
      acc[j * 8 + 0] = fmaf(acc[j * 8 + 0], corr, p * bflo(pk.x));
      acc[j * 8 + 1] = fmaf(acc[j * 8 + 1], corr, p * bfhi(pk.x));
      acc[j * 8 + 2] = fmaf(acc[j * 8 + 2], corr, p * bflo(pk.y));
      acc[j * 8 + 3] = fmaf(acc[j * 8 + 3], corr, p * bfhi(pk.y));
      acc[j * 8 + 4] = fmaf(acc[j * 8 + 4], corr, p * bflo(pk.z));
      acc[j * 8 + 5] = fmaf(acc[j * 8 + 5], corr, p * bfhi(pk.z));
      acc[j * 8 + 6] = fmaf(acc[j * 8 + 6], corr, p * bflo(pk.w));
      acc[j * 8 + 7] = fmaf(acc[j * 8 + 7], corr, p * bfhi(pk.w));
    }
  }

  const float inv = 1.f / lrun;
  unsigned short* orow = ao + (size_t)(b * NSEQ + n) * CDIM + h * 64 + dh * 32;
#pragma unroll
  for (int j = 0; j < 8; ++j) {
    ushort4 o;
    o.x = f2bfr(acc[j * 4 + 0] * inv);
    o.y = f2bfr(acc[j * 4 + 1] * inv);
    o.z = f2bfr(acc[j * 4 + 2] * inv);
    o.w = f2bfr(acc[j * 4 + 3] * inv);
    ((ushort4*)orow)[j] = o;
  }
}

// ---------------- launch ----------------
extern "C" void kernel_launch(void* const* d_in, const int* in_sizes, int n_in,
                              void* d_out, int out_size, void* d_ws,
                              size_t ws_size, hipStream_t stream) {
  (void)in_sizes; (void)n_in; (void)out_size; (void)ws_size;
  const float* x   = (const float*)d_in[0];
  const float* Wq1 = (const float*)d_in[1];
  const float* Wk1 = (const float*)d_in[2];
  const float* Wq2 = (const float*)d_in[3];
  const float* Wk2 = (const float*)d_in[4];
  const float* Wv  = (const float*)d_in[5];
  const float* Wo  = (const float*)d_in[6];
  const float* bo  = (const float*)d_in[7];
  float* out = (float*)d_out;

  char* ws = (char*)d_ws;
  unsigned short* xb   = (unsigned short*)(ws);              //  8,388,608 B
  unsigned short* Wall = (unsigned short*)(ws + 8388608);    //  2,883,584 B
  unsigned short* Wob  = (unsigned short*)(ws + 11272192);   //  2,097,152 B
  unsigned short* proj = (unsigned short*)(ws + 13369344);   // 11,534,336 B
  unsigned short* ao   = (unsigned short*)(ws + 24903680);   //  8,388,608 B

  auto cvt = [&](const float* s, unsigned short* d, int nelem) {
    const int nv = nelem >> 2;
    const int blocks = (nv + 255) / 256;
    cvt_kernel<<<dim3(blocks), dim3(256), 0, stream>>>(s, d, nv);
  };
  cvt(x, xb, MROWS * CDIM);
  cvt(Wq1, Wall + 0,      64 * 1024);
  cvt(Wk1, Wall + 65536,  64 * 1024);
  cvt(Wq2, Wall + 131072, 128 * 1024);
  cvt(Wk2, Wall + 262144, 128 * 1024);
  cvt(Wv,  Wall + 393216, 1024 * 1024);
  cvt(Wo,  Wob,           1024 * 1024);

  gemm_bt<0><<<dim3(NPROJ / 128, MROWS / 128), dim3(256), 0, stream>>>(
      xb, Wall, proj, (float*)nullptr, (const float*)nullptr, MROWS, NPROJ,
      CDIM);

  attn_scalar<<<dim3(BATCH * HHEADS * (NSEQ / 128)), dim3(256), 0, stream>>>(
      proj, ao);

  gemm_bt<1><<<dim3(CDIM / 128, MROWS / 128), dim3(256), 0, stream>>>(
      ao, Wob, (unsigned short*)nullptr, out, bo, MROWS, CDIM, CDIM);
}

// Round 2
// 237.440 us; speedup vs baseline: 6.2032x; 6.2032x over previous
//
#include <hip/hip_runtime.h>

// ---------------- problem constants ----------------
#define HHEADS 16
#define R1 4
#define R2 8
#define HD 64
#define CDIM 1024
#define NSEQ 2048
#define BATCH 2
#define NPROJ 1408            // 64 q1 + 64 k1 + 128 q2 + 128 k2 + 1024 v
#define MROWS (BATCH * NSEQ)  // 4096
#define SCALE 0.17677669529663687f  // (R1*R2)^-0.5

typedef __attribute__((ext_vector_type(8))) short bf16x8;
typedef __attribute__((ext_vector_type(4))) float f32x4;

// ---------------- bf16 helpers (raw ushort representation) ----------------
__device__ __forceinline__ float bflo(unsigned u) { return __uint_as_float(u << 16); }
__device__ __forceinline__ float bfhi(unsigned u) { return __uint_as_float(u & 0xffff0000u); }
__device__ __forceinline__ unsigned short f2bfr(float f) {
  unsigned u = __float_as_uint(f);
  u += 0x7fffu + ((u >> 16) & 1u);
  return (unsigned short)(u >> 16);
}
__device__ __forceinline__ unsigned pack2(float a, float b) {
  return (unsigned)f2bfr(a) | ((unsigned)f2bfr(b) << 16);
}

// ---------------- f32 -> bf16 conversion (vectorized) ----------------
__global__ void cvt_kernel(const float* __restrict__ src,
                           unsigned short* __restrict__ dst, int nvec) {
  for (int i = blockIdx.x * blockDim.x + threadIdx.x; i < nvec;
       i += gridDim.x * blockDim.x) {
    const float4 v = ((const float4*)src)[i];
    ushort4 o;
    o.x = f2bfr(v.x);
    o.y = f2bfr(v.y);
    o.z = f2bfr(v.z);
    o.w = f2bfr(v.w);
    ((ushort4*)dst)[i] = o;
  }
}

// ---------------- async global->LDS (16B per lane) ----------------
__device__ __forceinline__ void gld_lds16(const void* g, void* l) {
  __builtin_amdgcn_global_load_lds(
      (const __attribute__((address_space(1))) void*)g,
      (__attribute__((address_space(3))) void*)l, 16, 0, 0);
}

// ---------------- bf16 GEMM: C[M][N] = A[M][K] * Bw[N][K]^T ----------------
template <int OUTMODE>
__global__ __launch_bounds__(256) void gemm_bt(
    const unsigned short* __restrict__ A, const unsigned short* __restrict__ Bw,
    unsigned short* __restrict__ Cb, float* __restrict__ Cf,
    const float* __restrict__ bias, int M, int N, int K) {
  __shared__ unsigned short As[128 * 32];
  __shared__ unsigned short Bs[128 * 32];
  const int tid = threadIdx.x;
  const long brow = (long)blockIdx.y * 128;
  const long bcol = (long)blockIdx.x * 128;
  const int w = tid >> 6, lane = tid & 63;
  const int wr = w >> 1, wc = w & 1;
  const int lr = lane & 15, kg = lane >> 4;

  f32x4 acc[4][4];
#pragma unroll
  for (int m = 0; m < 4; ++m)
#pragma unroll
    for (int n = 0; n < 4; ++n) acc[m][n] = (f32x4){0.f, 0.f, 0.f, 0.f};

  const int off0 = tid * 16;
  const int row0 = off0 >> 6;
  const int kel0 = (off0 & 63) >> 1;

  const int nk = K >> 5;
  for (int kt = 0; kt < nk; ++kt) {
    const long kbase = (long)kt * 32 + kel0;
    gld_lds16(A + (brow + row0) * K + kbase, (char*)As + off0);
    gld_lds16(A + (brow + 64 + row0) * K + kbase, (char*)As + 4096 + off0);
    gld_lds16(Bw + (bcol + row0) * K + kbase, (char*)Bs + off0);
    gld_lds16(Bw + (bcol + 64 + row0) * K + kbase, (char*)Bs + 4096 + off0);
    __syncthreads();

    bf16x8 af[4], bfg[4];
#pragma unroll
    for (int m = 0; m < 4; ++m)
      af[m] = *(const bf16x8*)(As + (wr * 64 + m * 16 + lr) * 32 + kg * 8);
#pragma unroll
    for (int n = 0; n < 4; ++n)
      bfg[n] = *(const bf16x8*)(Bs + (wc * 64 + n * 16 + lr) * 32 + kg * 8);
#pragma unroll
    for (int m = 0; m < 4; ++m)
#pragma unroll
      for (int n = 0; n < 4; ++n)
        acc[m][n] = __builtin_amdgcn_mfma_f32_16x16x32_bf16(af[m], bfg[n],
                                                            acc[m][n], 0, 0, 0);
    __syncthreads();
  }

#pragma unroll
  for (int m = 0; m < 4; ++m) {
#pragma unroll
    for (int i = 0; i < 4; ++i) {
      const long r = brow + wr * 64 + m * 16 + kg * 4 + i;
#pragma unroll
      for (int n = 0; n < 4; ++n) {
        const long c = bcol + wc * 64 + n * 16 + lr;
        const float v = acc[m][n][i];
        if (OUTMODE == 1) {
          Cf[r * N + c] = v + bias[c];
        } else {
          Cb[r * N + c] = f2bfr(v);
        }
      }
    }
  }
}

// ---------------- kron feature build: qf/kf[bh][n][32] -------------------
// qf[r1*8+r2] = q1[r1]*q2[r2]*SCALE ; kf[r1*8+r2] = k1[r1]*k2[r2]
// (q1 (x) q2) . (k1 (x) k2) == (q1.k1)*(q2.k2) -> one K=32 MFMA per score tile
__global__ __launch_bounds__(256) void kron_kernel(
    const unsigned short* __restrict__ proj, unsigned short* __restrict__ qf,
    unsigned short* __restrict__ kf) {
  const int bh = blockIdx.x, b = bh >> 4, h = bh & 15;
  const int n = blockIdx.y * 256 + threadIdx.x;
  const unsigned short* row = proj + ((size_t)(b * NSEQ + n)) * NPROJ;
  float q1v[4], k1v[4], q2v[8], k2v[8];
  {
    const uint2 a = *(const uint2*)(row + h * 4);
    q1v[0] = bflo(a.x); q1v[1] = bfhi(a.x); q1v[2] = bflo(a.y); q1v[3] = bfhi(a.y);
    const uint2 c = *(const uint2*)(row + 64 + h * 4);
    k1v[0] = bflo(c.x); k1v[1] = bfhi(c.x); k1v[2] = bflo(c.y); k1v[3] = bfhi(c.y);
    const uint4 d = *(const uint4*)(row + 128 + h * 8);
    q2v[0] = bflo(d.x); q2v[1] = bfhi(d.x); q2v[2] = bflo(d.y); q2v[3] = bfhi(d.y);
    q2v[4] = bflo(d.z); q2v[5] = bfhi(d.z); q2v[6] = bflo(d.w); q2v[7] = bfhi(d.w);
    const uint4 e = *(const uint4*)(row + 256 + h * 8);
    k2v[0] = bflo(e.x); k2v[1] = bfhi(e.x); k2v[2] = bflo(e.y); k2v[3] = bfhi(e.y);
    k2v[4] = bflo(e.z); k2v[5] = bfhi(e.z); k2v[6] = bflo(e.w); k2v[7] = bfhi(e.w);
  }
  unsigned short* oq = qf + ((size_t)bh * NSEQ + n) * 32;
  unsigned short* ok = kf + ((size_t)bh * NSEQ + n) * 32;
#pragma unroll
  for (int i = 0; i < 4; ++i) {
    const float qs = q1v[i] * SCALE;
    uint4 uq, uk;
    uq.x = pack2(qs * q2v[0], qs * q2v[1]);
    uq.y = pack2(qs * q2v[2], qs * q2v[3]);
    uq.z = pack2(qs * q2v[4], qs * q2v[5]);
    uq.w = pack2(qs * q2v[6], qs * q2v[7]);
    uk.x = pack2(k1v[i] * k2v[0], k1v[i] * k2v[1]);
    uk.y = pack2(k1v[i] * k2v[2], k1v[i] * k2v[3]);
    uk.z = pack2(k1v[i] * k2v[4], k1v[i] * k2v[5]);
    uk.w = pack2(k1v[i] * k2v[6], k1v[i] * k2v[7]);
    *(uint4*)(oq + i * 8) = uq;
    *(uint4*)(ok + i * 8) = uk;
  }
}

// ---------------- V transpose: vt[bh][d][n] = proj[b,n][384+h*64+d] -------
// Coalesced reads (lanes span consecutive d), 16B stores (L2-merged).
__global__ __launch_bounds__(256) void vtrans_kernel(
    const unsigned short* __restrict__ proj, unsigned short* __restrict__ vt) {
  const int bh = blockIdx.y, b = bh >> 4, h = bh & 15;
  const int n0 = blockIdx.x * 64;
  const int tid = threadIdx.x;
#pragma unroll
  for (int it = 0; it < 2; ++it) {
    const int c = tid + it * 256;
    const int dd = c & 63;
    const int nn = (c >> 6) * 8;
    const unsigned short* src =
        proj + ((size_t)(b * NSEQ + n0 + nn)) * NPROJ + 384 + h * 64 + dd;
    unsigned short tmp[8];
#pragma unroll
    for (int j = 0; j < 8; ++j) tmp[j] = src[(size_t)j * NPROJ];
    uint4 u;
    u.x = (unsigned)tmp[0] | ((unsigned)tmp[1] << 16);
    u.y = (unsigned)tmp[2] | ((unsigned)tmp[3] << 16);
    u.z = (unsigned)tmp[4] | ((unsigned)tmp[5] << 16);
    u.w = (unsigned)tmp[6] | ((unsigned)tmp[7] << 16);
    *(uint4*)(vt + ((size_t)bh * 64 + dd) * NSEQ + n0 + nn) = u;
  }
}

// ---------------- MFMA flash attention ------------------------------------
// Wave = 16 query rows. Per 32-key tile: 2 score MFMAs (K=32 kron features),
// in-lane online softmax (16-lane shfl reduce), P->LDS->A-frag, 4 PV MFMAs
// against vt. Wave-local LDS (same-wave DS ops are in-order); no barriers.
__global__ __launch_bounds__(256) void attn_mfma(
    const unsigned short* __restrict__ qf, const unsigned short* __restrict__ kf,
    const unsigned short* __restrict__ vt, unsigned short* __restrict__ ao) {
  __shared__ unsigned short p_lds[4][512];
  const int tid = threadIdx.x;
  const int w = tid >> 6;
  const int lane = tid & 63;
  const int lr = lane & 15, kg = lane >> 4;
  const int bh = blockIdx.y;
  const int b = bh >> 4, h = bh & 15;
  const int qb = 31 - (int)blockIdx.x;  // heavy causal blocks first
  const int qbase = qb * 64 + w * 16;

  const unsigned short* qfh = qf + (size_t)bh * NSEQ * 32;
  const unsigned short* kfh = kf + (size_t)bh * NSEQ * 32;
  const unsigned short* vth = vt + (size_t)bh * 64 * NSEQ;

  const bf16x8 qfrag = *(const bf16x8*)(qfh + (qbase + lr) * 32 + kg * 8);
  const f32x4 zero = (f32x4){0.f, 0.f, 0.f, 0.f};
  f32x4 o[4];
  float mrun[4], lrun[4];
#pragma unroll
  for (int i = 0; i < 4; ++i) {
    o[i] = zero;
    mrun[i] = -1e30f;
    lrun[i] = 0.f;
  }

  const int nt = (qbase + 47) >> 5;  // this wave's causal tile count
  unsigned short* pw = p_lds[w] + kg * 128 + lr;
  const unsigned short* pr = p_lds[w] + lr * 32 + kg * 8;

  for (int kt = 0; kt < nt; ++kt) {
    const int k0 = kt * 32;
    const bf16x8 kfr0 = *(const bf16x8*)(kfh + (k0 + lr) * 32 + kg * 8);
    const bf16x8 kfr1 = *(const bf16x8*)(kfh + (k0 + 16 + lr) * 32 + kg * 8);
    f32x4 s0 = __builtin_amdgcn_mfma_f32_16x16x32_bf16(qfrag, kfr0, zero, 0, 0, 0);
    f32x4 s1 = __builtin_amdgcn_mfma_f32_16x16x32_bf16(qfrag, kfr1, zero, 0, 0, 0);

    if (k0 + 31 > qbase) {  // diagonal region: causal mask
      const int key0 = k0 + lr;
#pragma unroll
      for (int i = 0; i < 4; ++i) {
        const int r = qbase + kg * 4 + i;
        if (key0 > r) s0[i] = -1e30f;
        if (key0 + 16 > r) s1[i] = -1e30f;
      }
    }

#pragma unroll
    for (int i = 0; i < 4; ++i) {
      float mx = fmaxf(s0[i], s1[i]);
#pragma unroll
      for (int dlt = 1; dlt < 16; dlt <<= 1) mx = fmaxf(mx, __shfl_xor(mx, dlt));
      const float mn = fmaxf(mrun[i], mx);
      const float corr = __expf(mrun[i] - mn);
      mrun[i] = mn;
      s0[i] = __expf(s0[i] - mn);
      s1[i] = __expf(s1[i] - mn);
      float ps = s0[i] + s1[i];
#pragma unroll
      for (int dlt = 1; dlt < 16; dlt <<= 1) ps += __shfl_xor(ps, dlt);
      lrun[i] = lrun[i] * corr + ps;
      pw[i * 32] = f2bfr(s0[i]);
      pw[i * 32 + 16] = f2bfr(s1[i]);
#pragma unroll
      for (int dt = 0; dt < 4; ++dt) o[dt][i] *= corr;
    }

    __builtin_amdgcn_wave_barrier();  // pin DS write -> read program order
    const bf16x8 pfrag = *(const bf16x8*)pr;
#pragma unroll
    for (int dt = 0; dt < 4; ++dt) {
      const bf16x8 vfrag =
          *(const bf16x8*)(vth + (dt * 16 + lr) * NSEQ + k0 + kg * 8);
      o[dt] = __builtin_amdgcn_mfma_f32_16x16x32_bf16(pfrag, vfrag, o[dt], 0, 0, 0);
    }
    __builtin_amdgcn_wave_barrier();  // keep next writes after this read
  }

  float inv[4];
#pragma unroll
  for (int i = 0; i < 4; ++i) inv[i] = 1.f / lrun[i];
  unsigned short* aob =
      ao + ((size_t)(b * NSEQ + qbase + kg * 4)) * CDIM + h * 64 + lr;
#pragma unroll
  for (int i = 0; i < 4; ++i)
#pragma unroll
    for (int dt = 0; dt < 4; ++dt)
      aob[(size_t)i * CDIM + dt * 16] = f2bfr(o[dt][i] * inv[i]);
}

// ---------------- launch ----------------
extern "C" void kernel_launch(void* const* d_in, const int* in_sizes, int n_in,
                              void* d_out, int out_size, void* d_ws,
                              size_t ws_size, hipStream_t stream) {
  (void)in_sizes; (void)n_in; (void)out_size; (void)ws_size;
  const float* x   = (const float*)d_in[0];
  const float* Wq1 = (const float*)d_in[1];
  const float* Wk1 = (const float*)d_in[2];
  const float* Wq2 = (const float*)d_in[3];
  const float* Wk2 = (const float*)d_in[4];
  const float* Wv  = (const float*)d_in[5];
  const float* Wo  = (const float*)d_in[6];
  const float* bo  = (const float*)d_in[7];
  float* out = (float*)d_out;

  char* ws = (char*)d_ws;
  unsigned short* xb   = (unsigned short*)(ws);              // 8 MB (reused as ao)
  unsigned short* Wall = (unsigned short*)(ws + 8388608);    // 2,883,584 B
  unsigned short* Wob  = (unsigned short*)(ws + 11272192);   // 2 MB
  unsigned short* proj = (unsigned short*)(ws + 13369344);   // 11,534,336 B
  unsigned short* qf   = (unsigned short*)(ws + 24903680);   // 4 MB
  unsigned short* kf   = (unsigned short*)(ws + 29097984);   // 4 MB
  unsigned short* vt   = (unsigned short*)(ws + 33292288);   // 8 MB
  unsigned short* ao   = xb;  // xb dead after proj GEMM

  auto cvt = [&](const float* s, unsigned short* d, int nelem) {
    const int nv = nelem >> 2;
    cvt_kernel<<<dim3((nv + 255) / 256), dim3(256), 0, stream>>>(s, d, nv);
  };
  cvt(x, xb, MROWS * CDIM);
  cvt(Wq1, Wall + 0,      64 * 1024);
  cvt(Wk1, Wall + 65536,  64 * 1024);
  cvt(Wq2, Wall + 131072, 128 * 1024);
  cvt(Wk2, Wall + 262144, 128 * 1024);
  cvt(Wv,  Wall + 393216, 1024 * 1024);
  cvt(Wo,  Wob,           1024 * 1024);

  gemm_bt<0><<<dim3(NPROJ / 128, MROWS / 128), dim3(256), 0, stream>>>(
      xb, Wall, proj, (float*)nullptr, (const float*)nullptr, MROWS, NPROJ, CDIM);

  kron_kernel<<<dim3(BATCH * HHEADS, NSEQ / 256), dim3(256), 0, stream>>>(proj, qf, kf);
  vtrans_kernel<<<dim3(NSEQ / 64, BATCH * HHEADS), dim3(256), 0, stream>>>(proj, vt);

  attn_mfma<<<dim3(NSEQ / 64, BATCH * HHEADS), dim3(256), 0, stream>>>(qf, kf, vt, ao);

  gemm_bt<1><<<dim3(CDIM / 128, MROWS / 128), dim3(256), 0, stream>>>(
      ao, Wob, (unsigned short*)nullptr, out, bo, MROWS, CDIM, CDIM);
}

// Round 3
// 235.926 us; speedup vs baseline: 6.2430x; 1.0064x over previous
//
#include <hip/hip_runtime.h>

// ---------------- problem constants ----------------
#define HHEADS 16
#define R1 4
#define R2 8
#define HD 64
#define CDIM 1024
#define NSEQ 2048
#define BATCH 2
#define NPROJ 1408            // 64 q1 + 64 k1 + 128 q2 + 128 k2 + 1024 v
#define MROWS (BATCH * NSEQ)  // 4096
#define SCALE 0.17677669529663687f  // (R1*R2)^-0.5

typedef __attribute__((ext_vector_type(8))) short bf16x8;
typedef __attribute__((ext_vector_type(4))) float f32x4;
typedef __attribute__((ext_vector_type(4))) unsigned int u32x4;

// ---------------- bf16 helpers (raw ushort representation) ----------------
__device__ __forceinline__ float bflo(unsigned u) { return __uint_as_float(u << 16); }
__device__ __forceinline__ float bfhi(unsigned u) { return __uint_as_float(u & 0xffff0000u); }
__device__ __forceinline__ unsigned short f2bfr(float f) {
  unsigned u = __float_as_uint(f);
  u += 0x7fffu + ((u >> 16) & 1u);
  return (unsigned short)(u >> 16);
}
__device__ __forceinline__ unsigned pack2(float a, float b) {
  return (unsigned)f2bfr(a) | ((unsigned)f2bfr(b) << 16);
}

// ---------------- f32 -> bf16 conversion (vectorized) ----------------
__global__ void cvt_kernel(const float* __restrict__ src,
                           unsigned short* __restrict__ dst, int nvec) {
  for (int i = blockIdx.x * blockDim.x + threadIdx.x; i < nvec;
       i += gridDim.x * blockDim.x) {
    const float4 v = ((const float4*)src)[i];
    ushort4 o;
    o.x = f2bfr(v.x);
    o.y = f2bfr(v.y);
    o.z = f2bfr(v.z);
    o.w = f2bfr(v.w);
    ((ushort4*)dst)[i] = o;
  }
}

// ---------------- async global->LDS (16B per lane) ----------------
__device__ __forceinline__ void gld_lds16(const void* g, void* l) {
  __builtin_amdgcn_global_load_lds(
      (const __attribute__((address_space(1))) void*)g,
      (__attribute__((address_space(3))) void*)l, 16, 0, 0);
}

// ---------------- bf16 GEMM: C[M][N] = A[M][K] * Bw[N][K]^T ----------------
template <int OUTMODE>
__global__ __launch_bounds__(256) void gemm_bt(
    const unsigned short* __restrict__ A, const unsigned short* __restrict__ Bw,
    unsigned short* __restrict__ Cb, float* __restrict__ Cf,
    const float* __restrict__ bias, int M, int N, int K) {
  __shared__ unsigned short As[128 * 32];
  __shared__ unsigned short Bs[128 * 32];
  const int tid = threadIdx.x;
  const long brow = (long)blockIdx.y * 128;
  const long bcol = (long)blockIdx.x * 128;
  const int w = tid >> 6, lane = tid & 63;
  const int wr = w >> 1, wc = w & 1;
  const int lr = lane & 15, kg = lane >> 4;

  f32x4 acc[4][4];
#pragma unroll
  for (int m = 0; m < 4; ++m)
#pragma unroll
    for (int n = 0; n < 4; ++n) acc[m][n] = (f32x4){0.f, 0.f, 0.f, 0.f};

  const int off0 = tid * 16;
  const int row0 = off0 >> 6;
  const int kel0 = (off0 & 63) >> 1;

  const int nk = K >> 5;
  for (int kt = 0; kt < nk; ++kt) {
    const long kbase = (long)kt * 32 + kel0;
    gld_lds16(A + (brow + row0) * K + kbase, (char*)As + off0);
    gld_lds16(A + (brow + 64 + row0) * K + kbase, (char*)As + 4096 + off0);
    gld_lds16(Bw + (bcol + row0) * K + kbase, (char*)Bs + off0);
    gld_lds16(Bw + (bcol + 64 + row0) * K + kbase, (char*)Bs + 4096 + off0);
    __syncthreads();

    bf16x8 af[4], bfg[4];
#pragma unroll
    for (int m = 0; m < 4; ++m)
      af[m] = *(const bf16x8*)(As + (wr * 64 + m * 16 + lr) * 32 + kg * 8);
#pragma unroll
    for (int n = 0; n < 4; ++n)
      bfg[n] = *(const bf16x8*)(Bs + (wc * 64 + n * 16 + lr) * 32 + kg * 8);
#pragma unroll
    for (int m = 0; m < 4; ++m)
#pragma unroll
      for (int n = 0; n < 4; ++n)
        acc[m][n] = __builtin_amdgcn_mfma_f32_16x16x32_bf16(af[m], bfg[n],
                                                            acc[m][n], 0, 0, 0);
    __syncthreads();
  }

#pragma unroll
  for (int m = 0; m < 4; ++m) {
#pragma unroll
    for (int i = 0; i < 4; ++i) {
      const long r = brow + wr * 64 + m * 16 + kg * 4 + i;
#pragma unroll
      for (int n = 0; n < 4; ++n) {
        const long c = bcol + wc * 64 + n * 16 + lr;
        const float v = acc[m][n][i];
        if (OUTMODE == 1) {
          Cf[r * N + c] = v + bias[c];
        } else {
          Cb[r * N + c] = f2bfr(v);
        }
      }
    }
  }
}

// ---------------- kron feature build: qf/kf[bh][n][32] -------------------
// qf[r1*8+r2] = q1[r1]*q2[r2]*SCALE ; kf[r1*8+r2] = k1[r1]*k2[r2]
// (q1 (x) q2) . (k1 (x) k2) == (q1.k1)*(q2.k2) -> one K=32 MFMA per score tile
__global__ __launch_bounds__(256) void kron_kernel(
    const unsigned short* __restrict__ proj, unsigned short* __restrict__ qf,
    unsigned short* __restrict__ kf) {
  const int bh = blockIdx.x, b = bh >> 4, h = bh & 15;
  const int n = blockIdx.y * 256 + threadIdx.x;
  const unsigned short* row = proj + ((size_t)(b * NSEQ + n)) * NPROJ;
  float q1v[4], k1v[4], q2v[8], k2v[8];
  {
    const uint2 a = *(const uint2*)(row + h * 4);
    q1v[0] = bflo(a.x); q1v[1] = bfhi(a.x); q1v[2] = bflo(a.y); q1v[3] = bfhi(a.y);
    const uint2 c = *(const uint2*)(row + 64 + h * 4);
    k1v[0] = bflo(c.x); k1v[1] = bfhi(c.x); k1v[2] = bflo(c.y); k1v[3] = bfhi(c.y);
    const uint4 d = *(const uint4*)(row + 128 + h * 8);
    q2v[0] = bflo(d.x); q2v[1] = bfhi(d.x); q2v[2] = bflo(d.y); q2v[3] = bfhi(d.y);
    q2v[4] = bflo(d.z); q2v[5] = bfhi(d.z); q2v[6] = bflo(d.w); q2v[7] = bfhi(d.w);
    const uint4 e = *(const uint4*)(row + 256 + h * 8);
    k2v[0] = bflo(e.x); k2v[1] = bfhi(e.x); k2v[2] = bflo(e.y); k2v[3] = bfhi(e.y);
    k2v[4] = bflo(e.z); k2v[5] = bfhi(e.z); k2v[6] = bflo(e.w); k2v[7] = bfhi(e.w);
  }
  unsigned short* oq = qf + ((size_t)bh * NSEQ + n) * 32;
  unsigned short* ok = kf + ((size_t)bh * NSEQ + n) * 32;
#pragma unroll
  for (int i = 0; i < 4; ++i) {
    const float qs = q1v[i] * SCALE;
    uint4 uq, uk;
    uq.x = pack2(qs * q2v[0], qs * q2v[1]);
    uq.y = pack2(qs * q2v[2], qs * q2v[3]);
    uq.z = pack2(qs * q2v[4], qs * q2v[5]);
    uq.w = pack2(qs * q2v[6], qs * q2v[7]);
    uk.x = pack2(k1v[i] * k2v[0], k1v[i] * k2v[1]);
    uk.y = pack2(k1v[i] * k2v[2], k1v[i] * k2v[3]);
    uk.z = pack2(k1v[i] * k2v[4], k1v[i] * k2v[5]);
    uk.w = pack2(k1v[i] * k2v[6], k1v[i] * k2v[7]);
    *(uint4*)(oq + i * 8) = uq;
    *(uint4*)(ok + i * 8) = uk;
  }
}

// ---------------- V transpose: vt[bh][d][n] = proj[b,n][384+h*64+d] -------
__global__ __launch_bounds__(256) void vtrans_kernel(
    const unsigned short* __restrict__ proj, unsigned short* __restrict__ vt) {
  const int bh = blockIdx.y, b = bh >> 4, h = bh & 15;
  const int n0 = blockIdx.x * 64;
  const int tid = threadIdx.x;
#pragma unroll
  for (int it = 0; it < 2; ++it) {
    const int c = tid + it * 256;
    const int dd = c & 63;
    const int nn = (c >> 6) * 8;
    const unsigned short* src =
        proj + ((size_t)(b * NSEQ + n0 + nn)) * NPROJ + 384 + h * 64 + dd;
    unsigned short tmp[8];
#pragma unroll
    for (int j = 0; j < 8; ++j) tmp[j] = src[(size_t)j * NPROJ];
    uint4 u;
    u.x = (unsigned)tmp[0] | ((unsigned)tmp[1] << 16);
    u.y = (unsigned)tmp[2] | ((unsigned)tmp[3] << 16);
    u.z = (unsigned)tmp[4] | ((unsigned)tmp[5] << 16);
    u.w = (unsigned)tmp[6] | ((unsigned)tmp[7] << 16);
    *(uint4*)(vt + ((size_t)bh * 64 + dd) * NSEQ + n0 + nn) = u;
  }
}

// ---------------- MFMA flash attention (swapped operands, all in-lane) -----
// Score: S = mfma(A=kf, B=qf) -> C col = lane&15 = q-row, C rows = keys.
// Key-row permutation krow=(lr>>2)*8+(lr&3): s0 covers keys {kg*8..kg*8+3},
// s1 covers {kg*8+4..kg*8+7} -> lane holds keys kg*8..kg*8+7 of its q-row,
// which IS the B-fragment layout for the PV MFMA (B[k=kg*8+j][col=q=lr]).
// PV swapped: o = mfma(A=vt-frag, B=p-frag) -> O^T, col = q = lane&15, so
// softmax stats/rescale/normalize are lane-uniform. No LDS, 2 shfl per tile.
__global__ __launch_bounds__(256) void attn_mfma(
    const unsigned short* __restrict__ qf, const unsigned short* __restrict__ kf,
    const unsigned short* __restrict__ vt, unsigned short* __restrict__ ao) {
  const int tid = threadIdx.x;
  const int w = tid >> 6;
  const int lane = tid & 63;
  const int lr = lane & 15, kg = lane >> 4;
  const int bh = blockIdx.y;
  const int b = bh >> 4, h = bh & 15;
  const int qb = 31 - (int)blockIdx.x;  // heavy causal blocks first
  const int qbase = qb * 64 + w * 16;
  const int q = qbase + lr;

  const unsigned short* qfh = qf + (size_t)bh * NSEQ * 32;
  const unsigned short* kfh = kf + (size_t)bh * NSEQ * 32;
  const unsigned short* vth = vt + (size_t)bh * 64 * NSEQ;

  const bf16x8 qfrag = *(const bf16x8*)(qfh + (q) * 32 + kg * 8);
  const int krow = (lr >> 2) * 8 + (lr & 3);  // permuted key row for A-frag
  const f32x4 zero = (f32x4){0.f, 0.f, 0.f, 0.f};

  f32x4 o[4];
#pragma unroll
  for (int dt = 0; dt < 4; ++dt) o[dt] = zero;
  float mrun = -1e30f;
  float lsum = 0.f;  // per-lane partial (this lane's 8 keys); reduced at end

  const int nt = (qbase + 47) >> 5;
  for (int kt = 0; kt < nt; ++kt) {
    const int k0 = kt * 32;
    const bf16x8 kfr0 = *(const bf16x8*)(kfh + (k0 + krow) * 32 + kg * 8);
    const bf16x8 kfr1 = *(const bf16x8*)(kfh + (k0 + krow + 4) * 32 + kg * 8);
    f32x4 s0 = __builtin_amdgcn_mfma_f32_16x16x32_bf16(kfr0, qfrag, zero, 0, 0, 0);
    f32x4 s1 = __builtin_amdgcn_mfma_f32_16x16x32_bf16(kfr1, qfrag, zero, 0, 0, 0);
    // s0[i] = S[key=k0+kg*8+i][q], s1[i] = S[key=k0+kg*8+4+i][q]

    if (k0 + 31 > qbase) {  // diagonal region: causal mask
      const int kb = k0 + kg * 8;
#pragma unroll
      for (int i = 0; i < 4; ++i) {
        if (kb + i > q) s0[i] = -1e30f;
        if (kb + 4 + i > q) s1[i] = -1e30f;
      }
    }

    float mx = fmaxf(fmaxf(fmaxf(s0[0], s0[1]), fmaxf(s0[2], s0[3])),
                     fmaxf(fmaxf(s1[0], s1[1]), fmaxf(s1[2], s1[3])));
    mx = fmaxf(mx, __shfl_xor(mx, 16));
    mx = fmaxf(mx, __shfl_xor(mx, 32));

    if (!__all(mx <= mrun + 8.f)) {  // defer-max (T13): rescale only on growth
      const float mn = fmaxf(mrun, mx);
      const float corr = __expf(mrun - mn);  // first tile: exp(-inf) = 0
      mrun = mn;
      lsum *= corr;
#pragma unroll
      for (int dt = 0; dt < 4; ++dt) {
        o[dt][0] *= corr; o[dt][1] *= corr; o[dt][2] *= corr; o[dt][3] *= corr;
      }
    }

    const float p0 = __expf(s0[0] - mrun), p1 = __expf(s0[1] - mrun);
    const float p2 = __expf(s0[2] - mrun), p3 = __expf(s0[3] - mrun);
    const float p4 = __expf(s1[0] - mrun), p5 = __expf(s1[1] - mrun);
    const float p6 = __expf(s1[2] - mrun), p7 = __expf(s1[3] - mrun);
    lsum += ((p0 + p1) + (p2 + p3)) + ((p4 + p5) + (p6 + p7));

    union { u32x4 u; bf16x8 h; } pc;
    pc.u = (u32x4){pack2(p0, p1), pack2(p2, p3), pack2(p4, p5), pack2(p6, p7)};

#pragma unroll
    for (int dt = 0; dt < 4; ++dt) {
      const bf16x8 vfr =
          *(const bf16x8*)(vth + (dt * 16 + lr) * NSEQ + k0 + kg * 8);
      o[dt] = __builtin_amdgcn_mfma_f32_16x16x32_bf16(vfr, pc.h, o[dt], 0, 0, 0);
      // o[dt][i] = O^T[d = dt*16 + kg*4 + i][q]
    }
  }

  float lt = lsum + __shfl_xor(lsum, 16);
  lt += __shfl_xor(lt, 32);
  const float inv = 1.f / lt;

  unsigned short* aob = ao + ((size_t)(b * NSEQ + q)) * CDIM + h * 64 + kg * 4;
#pragma unroll
  for (int dt = 0; dt < 4; ++dt) {
    uint2 u;
    u.x = pack2(o[dt][0] * inv, o[dt][1] * inv);
    u.y = pack2(o[dt][2] * inv, o[dt][3] * inv);
    *(uint2*)(aob + dt * 16) = u;
  }
}

// ---------------- launch ----------------
extern "C" void kernel_launch(void* const* d_in, const int* in_sizes, int n_in,
                              void* d_out, int out_size, void* d_ws,
                              size_t ws_size, hipStream_t stream) {
  (void)in_sizes; (void)n_in; (void)out_size; (void)ws_size;
  const float* x   = (const float*)d_in[0];
  const float* Wq1 = (const float*)d_in[1];
  const float* Wk1 = (const float*)d_in[2];
  const float* Wq2 = (const float*)d_in[3];
  const float* Wk2 = (const float*)d_in[4];
  const float* Wv  = (const float*)d_in[5];
  const float* Wo  = (const float*)d_in[6];
  const float* bo  = (const float*)d_in[7];
  float* out = (float*)d_out;

  char* ws = (char*)d_ws;
  unsigned short* xb   = (unsigned short*)(ws);              // 8 MB (reused as ao)
  unsigned short* Wall = (unsigned short*)(ws + 8388608);    // 2,883,584 B
  unsigned short* Wob  = (unsigned short*)(ws + 11272192);   // 2 MB
  unsigned short* proj = (unsigned short*)(ws + 13369344);   // 11,534,336 B
  unsigned short* qf   = (unsigned short*)(ws + 24903680);   // 4 MB
  unsigned short* kf   = (unsigned short*)(ws + 29097984);   // 4 MB
  unsigned short* vt   = (unsigned short*)(ws + 33292288);   // 8 MB
  unsigned short* ao   = xb;  // xb dead after proj GEMM

  auto cvt = [&](const float* s, unsigned short* d, int nelem) {
    const int nv = nelem >> 2;
    cvt_kernel<<<dim3((nv + 255) / 256), dim3(256), 0, stream>>>(s, d, nv);
  };
  cvt(x, xb, MROWS * CDIM);
  cvt(Wq1, Wall + 0,      64 * 1024);
  cvt(Wk1, Wall + 65536,  64 * 1024);
  cvt(Wq2, Wall + 131072, 128 * 1024);
  cvt(Wk2, Wall + 262144, 128 * 1024);
  cvt(Wv,  Wall + 393216, 1024 * 1024);
  cvt(Wo,  Wob,           1024 * 1024);

  gemm_bt<0><<<dim3(NPROJ / 128, MROWS / 128), dim3(256), 0, stream>>>(
      xb, Wall, proj, (float*)nullptr, (const float*)nullptr, MROWS, NPROJ, CDIM);

  kron_kernel<<<dim3(BATCH * HHEADS, NSEQ / 256), dim3(256), 0, stream>>>(proj, qf, kf);
  vtrans_kernel<<<dim3(NSEQ / 64, BATCH * HHEADS), dim3(256), 0, stream>>>(proj, vt);

  attn_mfma<<<dim3(NSEQ / 64, BATCH * HHEADS), dim3(256), 0, stream>>>(qf, kf, vt, ao);

  gemm_bt<1><<<dim3(CDIM / 128, MROWS / 128), dim3(256), 0, stream>>>(
      ao, Wob, (unsigned short*)nullptr, out, bo, MROWS, CDIM, CDIM);
}

// Round 4
// 172.206 us; speedup vs baseline: 8.5530x; 1.3700x over previous
//
#include <hip/hip_runtime.h>

// ---------------- problem constants ----------------
#define HHEADS 16
#define R1 4
#define R2 8
#define HD 64
#define CDIM 1024
#define NSEQ 2048
#define BATCH 2
#define NPROJ 1408            // 64 q1 + 64 k1 + 128 q2 + 128 k2 + 1024 v
#define MROWS (BATCH * NSEQ)  // 4096
#define SCALE 0.17677669529663687f  // (R1*R2)^-0.5

typedef __attribute__((ext_vector_type(8))) short bf16x8;
typedef __attribute__((ext_vector_type(4))) float f32x4;
typedef __attribute__((ext_vector_type(4))) unsigned int u32x4;

// ---------------- bf16 helpers (raw ushort representation) ----------------
__device__ __forceinline__ float bflo(unsigned u) { return __uint_as_float(u << 16); }
__device__ __forceinline__ float bfhi(unsigned u) { return __uint_as_float(u & 0xffff0000u); }
__device__ __forceinline__ unsigned short f2bfr(float f) {
  unsigned u = __float_as_uint(f);
  u += 0x7fffu + ((u >> 16) & 1u);
  return (unsigned short)(u >> 16);
}
__device__ __forceinline__ unsigned pack2(float a, float b) {
  return (unsigned)f2bfr(a) | ((unsigned)f2bfr(b) << 16);
}
// hardware packed f32x2 -> bf16x2 (RNE), single instruction (T12 recipe)
__device__ __forceinline__ unsigned cvtpk(float a, float b) {
  unsigned r;
  asm("v_cvt_pk_bf16_f32 %0, %1, %2" : "=v"(r) : "v"(a), "v"(b));
  return r;
}

// ---------------- f32 -> bf16 conversion (vectorized) ----------------
__global__ void cvt_kernel(const float* __restrict__ src,
                           unsigned short* __restrict__ dst, int nvec) {
  for (int i = blockIdx.x * blockDim.x + threadIdx.x; i < nvec;
       i += gridDim.x * blockDim.x) {
    const float4 v = ((const float4*)src)[i];
    ushort4 o;
    o.x = f2bfr(v.x);
    o.y = f2bfr(v.y);
    o.z = f2bfr(v.z);
    o.w = f2bfr(v.w);
    ((ushort4*)dst)[i] = o;
  }
}

// ---------------- async global->LDS (16B per lane) ----------------
__device__ __forceinline__ void gld_lds16(const void* g, void* l) {
  __builtin_amdgcn_global_load_lds(
      (const __attribute__((address_space(1))) void*)g,
      (__attribute__((address_space(3))) void*)l, 16, 0, 0);
}

// ---------------- bf16 GEMM: C[M][N] = A[M][K] * Bw[N][K]^T ----------------
template <int OUTMODE>
__global__ __launch_bounds__(256) void gemm_bt(
    const unsigned short* __restrict__ A, const unsigned short* __restrict__ Bw,
    unsigned short* __restrict__ Cb, float* __restrict__ Cf,
    const float* __restrict__ bias, int M, int N, int K) {
  __shared__ unsigned short As[128 * 32];
  __shared__ unsigned short Bs[128 * 32];
  const int tid = threadIdx.x;
  const long brow = (long)blockIdx.y * 128;
  const long bcol = (long)blockIdx.x * 128;
  const int w = tid >> 6, lane = tid & 63;
  const int wr = w >> 1, wc = w & 1;
  const int lr = lane & 15, kg = lane >> 4;

  f32x4 acc[4][4];
#pragma unroll
  for (int m = 0; m < 4; ++m)
#pragma unroll
    for (int n = 0; n < 4; ++n) acc[m][n] = (f32x4){0.f, 0.f, 0.f, 0.f};

  const int off0 = tid * 16;
  const int row0 = off0 >> 6;
  const int kel0 = (off0 & 63) >> 1;

  const int nk = K >> 5;
  for (int kt = 0; kt < nk; ++kt) {
    const long kbase = (long)kt * 32 + kel0;
    gld_lds16(A + (brow + row0) * K + kbase, (char*)As + off0);
    gld_lds16(A + (brow + 64 + row0) * K + kbase, (char*)As + 4096 + off0);
    gld_lds16(Bw + (bcol + row0) * K + kbase, (char*)Bs + off0);
    gld_lds16(Bw + (bcol + 64 + row0) * K + kbase, (char*)Bs + 4096 + off0);
    __syncthreads();

    bf16x8 af[4], bfg[4];
#pragma unroll
    for (int m = 0; m < 4; ++m)
      af[m] = *(const bf16x8*)(As + (wr * 64 + m * 16 + lr) * 32 + kg * 8);
#pragma unroll
    for (int n = 0; n < 4; ++n)
      bfg[n] = *(const bf16x8*)(Bs + (wc * 64 + n * 16 + lr) * 32 + kg * 8);
#pragma unroll
    for (int m = 0; m < 4; ++m)
#pragma unroll
      for (int n = 0; n < 4; ++n)
        acc[m][n] = __builtin_amdgcn_mfma_f32_16x16x32_bf16(af[m], bfg[n],
                                                            acc[m][n], 0, 0, 0);
    __syncthreads();
  }

#pragma unroll
  for (int m = 0; m < 4; ++m) {
#pragma unroll
    for (int i = 0; i < 4; ++i) {
      const long r = brow + wr * 64 + m * 16 + kg * 4 + i;
#pragma unroll
      for (int n = 0; n < 4; ++n) {
        const long c = bcol + wc * 64 + n * 16 + lr;
        const float v = acc[m][n][i];
        if (OUTMODE == 1) {
          Cf[r * N + c] = v + bias[c];
        } else {
          Cb[r * N + c] = f2bfr(v);
        }
      }
    }
  }
}

// ---------------- kron feature build: qf/kf[bh][n][32] -------------------
__global__ __launch_bounds__(256) void kron_kernel(
    const unsigned short* __restrict__ proj, unsigned short* __restrict__ qf,
    unsigned short* __restrict__ kf) {
  const int bh = blockIdx.x, b = bh >> 4, h = bh & 15;
  const int n = blockIdx.y * 256 + threadIdx.x;
  const unsigned short* row = proj + ((size_t)(b * NSEQ + n)) * NPROJ;
  float q1v[4], k1v[4], q2v[8], k2v[8];
  {
    const uint2 a = *(const uint2*)(row + h * 4);
    q1v[0] = bflo(a.x); q1v[1] = bfhi(a.x); q1v[2] = bflo(a.y); q1v[3] = bfhi(a.y);
    const uint2 c = *(const uint2*)(row + 64 + h * 4);
    k1v[0] = bflo(c.x); k1v[1] = bfhi(c.x); k1v[2] = bflo(c.y); k1v[3] = bfhi(c.y);
    const uint4 d = *(const uint4*)(row + 128 + h * 8);
    q2v[0] = bflo(d.x); q2v[1] = bfhi(d.x); q2v[2] = bflo(d.y); q2v[3] = bfhi(d.y);
    q2v[4] = bflo(d.z); q2v[5] = bfhi(d.z); q2v[6] = bflo(d.w); q2v[7] = bfhi(d.w);
    const uint4 e = *(const uint4*)(row + 256 + h * 8);
    k2v[0] = bflo(e.x); k2v[1] = bfhi(e.x); k2v[2] = bflo(e.y); k2v[3] = bfhi(e.y);
    k2v[4] = bflo(e.z); k2v[5] = bfhi(e.z); k2v[6] = bflo(e.w); k2v[7] = bfhi(e.w);
  }
  unsigned short* oq = qf + ((size_t)bh * NSEQ + n) * 32;
  unsigned short* ok = kf + ((size_t)bh * NSEQ + n) * 32;
#pragma unroll
  for (int i = 0; i < 4; ++i) {
    const float qs = q1v[i] * SCALE;
    uint4 uq, uk;
    uq.x = pack2(qs * q2v[0], qs * q2v[1]);
    uq.y = pack2(qs * q2v[2], qs * q2v[3]);
    uq.z = pack2(qs * q2v[4], qs * q2v[5]);
    uq.w = pack2(qs * q2v[6], qs * q2v[7]);
    uk.x = pack2(k1v[i] * k2v[0], k1v[i] * k2v[1]);
    uk.y = pack2(k1v[i] * k2v[2], k1v[i] * k2v[3]);
    uk.z = pack2(k1v[i] * k2v[4], k1v[i] * k2v[5]);
    uk.w = pack2(k1v[i] * k2v[6], k1v[i] * k2v[7]);
    *(uint4*)(oq + i * 8) = uq;
    *(uint4*)(ok + i * 8) = uk;
  }
}

// ---------------- V transpose: vt[bh][d][n] = proj[b,n][384+h*64+d] -------
__global__ __launch_bounds__(256) void vtrans_kernel(
    const unsigned short* __restrict__ proj, unsigned short* __restrict__ vt) {
  const int bh = blockIdx.y, b = bh >> 4, h = bh & 15;
  const int n0 = blockIdx.x * 64;
  const int tid = threadIdx.x;
#pragma unroll
  for (int it = 0; it < 2; ++it) {
    const int c = tid + it * 256;
    const int dd = c & 63;
    const int nn = (c >> 6) * 8;
    const unsigned short* src =
        proj + ((size_t)(b * NSEQ + n0 + nn)) * NPROJ + 384 + h * 64 + dd;
    unsigned short tmp[8];
#pragma unroll
    for (int j = 0; j < 8; ++j) tmp[j] = src[(size_t)j * NPROJ];
    uint4 u;
    u.x = (unsigned)tmp[0] | ((unsigned)tmp[1] << 16);
    u.y = (unsigned)tmp[2] | ((unsigned)tmp[3] << 16);
    u.z = (unsigned)tmp[4] | ((unsigned)tmp[5] << 16);
    u.w = (unsigned)tmp[6] | ((unsigned)tmp[7] << 16);
    *(uint4*)(vt + ((size_t)bh * 64 + dd) * NSEQ + n0 + nn) = u;
  }
}

// ---------------- MFMA flash attention (swapped, 32 q-rows/wave, pipelined)
// One wave per block. Wave owns 32 q rows (two 16-row B-fragments qA/qB).
// Per 32-key tile: 6 loads feed 12 MFMAs (4 score + 8 PV). Tile kt+1's
// loads are issued BEFORE tile kt's compute (register double-buffer) so the
// L2 gather latency hides under softmax+PV. Common path has NO cross-lane
// ops: lane-local max check via __all; shfl reduce only on max growth.
// Only the final tile (nt-1) is causal-masked (nt = qb+1 exactly).
__global__ __launch_bounds__(64) void attn_mfma(
    const unsigned short* __restrict__ qf, const unsigned short* __restrict__ kf,
    const unsigned short* __restrict__ vt, unsigned short* __restrict__ ao) {
  const int lane = threadIdx.x;
  const int lr = lane & 15, kg = lane >> 4;
  const int bh = blockIdx.y;
  const int b = bh >> 4, h = bh & 15;
  const int qb = 63 - (int)blockIdx.x;  // heavy causal blocks first
  const int qbase = qb * 32;
  const int q0 = qbase + lr;
  const int q1 = qbase + 16 + lr;

  const unsigned short* qfh = qf + (size_t)bh * NSEQ * 32;
  const unsigned short* kfh = kf + (size_t)bh * NSEQ * 32;
  const unsigned short* vth = vt + (size_t)bh * 64 * NSEQ;

  const bf16x8 qA = *(const bf16x8*)(qfh + q0 * 32 + kg * 8);
  const bf16x8 qB = *(const bf16x8*)(qfh + q1 * 32 + kg * 8);
  const int krow = (lr >> 2) * 8 + (lr & 3);  // permuted key row for A-frag
  const int kof0 = krow * 32 + kg * 8;
  const int kof1 = kof0 + 4 * 32;
  const int vof0 = (0 * 16 + lr) * NSEQ + kg * 8;
  const int vof1 = (1 * 16 + lr) * NSEQ + kg * 8;
  const int vof2 = (2 * 16 + lr) * NSEQ + kg * 8;
  const int vof3 = (3 * 16 + lr) * NSEQ + kg * 8;
  const f32x4 zero = (f32x4){0.f, 0.f, 0.f, 0.f};

  f32x4 oA[4], oB[4];
#pragma unroll
  for (int dt = 0; dt < 4; ++dt) { oA[dt] = zero; oB[dt] = zero; }
  float mA = -1e30f, mB = -1e30f, lAs = 0.f, lBs = 0.f;

  const int nt = qb + 1;
  // prime the pipeline: tile 0 fragments
  bf16x8 ck0 = *(const bf16x8*)(kfh + kof0);
  bf16x8 ck1 = *(const bf16x8*)(kfh + kof1);
  bf16x8 cv0 = *(const bf16x8*)(vth + vof0);
  bf16x8 cv1 = *(const bf16x8*)(vth + vof1);
  bf16x8 cv2 = *(const bf16x8*)(vth + vof2);
  bf16x8 cv3 = *(const bf16x8*)(vth + vof3);

  for (int kt = 0; kt < nt; ++kt) {
    // ---- issue next tile's loads (clamped; last iter re-loads, harmless)
    const int kn = (kt + 1 < nt ? kt + 1 : nt - 1) * 32;
    const bf16x8 nk0 = *(const bf16x8*)(kfh + kn * 32 + kof0);
    const bf16x8 nk1 = *(const bf16x8*)(kfh + kn * 32 + kof1);
    const bf16x8 nv0 = *(const bf16x8*)(vth + vof0 + kn);
    const bf16x8 nv1 = *(const bf16x8*)(vth + vof1 + kn);
    const bf16x8 nv2 = *(const bf16x8*)(vth + vof2 + kn);
    const bf16x8 nv3 = *(const bf16x8*)(vth + vof3 + kn);

    // ---- scores: s{A,B}0[i] = S[key kt*32+kg*8+i][q], s{A,B}1: keys +4
    f32x4 sA0 = __builtin_amdgcn_mfma_f32_16x16x32_bf16(ck0, qA, zero, 0, 0, 0);
    f32x4 sA1 = __builtin_amdgcn_mfma_f32_16x16x32_bf16(ck1, qA, zero, 0, 0, 0);
    f32x4 sB0 = __builtin_amdgcn_mfma_f32_16x16x32_bf16(ck0, qB, zero, 0, 0, 0);
    f32x4 sB1 = __builtin_amdgcn_mfma_f32_16x16x32_bf16(ck1, qB, zero, 0, 0, 0);

    if (kt == nt - 1) {  // diagonal tile: causal mask
      const int kb = kt * 32 + kg * 8;
#pragma unroll
      for (int i = 0; i < 4; ++i) {
        if (kb + i > q0) sA0[i] = -1e30f;
        if (kb + 4 + i > q0) sA1[i] = -1e30f;
        if (kb + i > q1) sB0[i] = -1e30f;
        if (kb + 4 + i > q1) sB1[i] = -1e30f;
      }
    }

    // ---- lane-local max check; cross-lane reduce ONLY on growth
    const float mxA = fmaxf(fmaxf(fmaxf(sA0[0], sA0[1]), fmaxf(sA0[2], sA0[3])),
                            fmaxf(fmaxf(sA1[0], sA1[1]), fmaxf(sA1[2], sA1[3])));
    const float mxB = fmaxf(fmaxf(fmaxf(sB0[0], sB0[1]), fmaxf(sB0[2], sB0[3])),
                            fmaxf(fmaxf(sB1[0], sB1[1]), fmaxf(sB1[2], sB1[3])));
    const bool ok = (mxA <= mA + 8.f) && (mxB <= mB + 8.f);
    if (!__all(ok)) {
      float rA = fmaxf(mxA, __shfl_xor(mxA, 16));
      rA = fmaxf(rA, __shfl_xor(rA, 32));
      float rB = fmaxf(mxB, __shfl_xor(mxB, 16));
      rB = fmaxf(rB, __shfl_xor(rB, 32));
      const float nmA = fmaxf(mA, rA), nmB = fmaxf(mB, rB);
      const float cA = __expf(mA - nmA), cB = __expf(mB - nmB);
      mA = nmA; mB = nmB;
      lAs *= cA; lBs *= cB;
#pragma unroll
      for (int dt = 0; dt < 4; ++dt) {
        oA[dt][0] *= cA; oA[dt][1] *= cA; oA[dt][2] *= cA; oA[dt][3] *= cA;
        oB[dt][0] *= cB; oB[dt][1] *= cB; oB[dt][2] *= cB; oB[dt][3] *= cB;
      }
    }

    const float a0 = __expf(sA0[0] - mA), a1 = __expf(sA0[1] - mA);
    const float a2 = __expf(sA0[2] - mA), a3 = __expf(sA0[3] - mA);
    const float a4 = __expf(sA1[0] - mA), a5 = __expf(sA1[1] - mA);
    const float a6 = __expf(sA1[2] - mA), a7 = __expf(sA1[3] - mA);
    const float b0 = __expf(sB0[0] - mB), b1 = __expf(sB0[1] - mB);
    const float b2 = __expf(sB0[2] - mB), b3 = __expf(sB0[3] - mB);
    const float b4 = __expf(sB1[0] - mB), b5 = __expf(sB1[1] - mB);
    const float b6 = __expf(sB1[2] - mB), b7 = __expf(sB1[3] - mB);
    lAs += ((a0 + a1) + (a2 + a3)) + ((a4 + a5) + (a6 + a7));
    lBs += ((b0 + b1) + (b2 + b3)) + ((b4 + b5) + (b6 + b7));

    union { u32x4 u; bf16x8 hv; } pA, pB;
    pA.u = (u32x4){cvtpk(a0, a1), cvtpk(a2, a3), cvtpk(a4, a5), cvtpk(a6, a7)};
    pB.u = (u32x4){cvtpk(b0, b1), cvtpk(b2, b3), cvtpk(b4, b5), cvtpk(b6, b7)};

    oA[0] = __builtin_amdgcn_mfma_f32_16x16x32_bf16(cv0, pA.hv, oA[0], 0, 0, 0);
    oB[0] = __builtin_amdgcn_mfma_f32_16x16x32_bf16(cv0, pB.hv, oB[0], 0, 0, 0);
    oA[1] = __builtin_amdgcn_mfma_f32_16x16x32_bf16(cv1, pA.hv, oA[1], 0, 0, 0);
    oB[1] = __builtin_amdgcn_mfma_f32_16x16x32_bf16(cv1, pB.hv, oB[1], 0, 0, 0);
    oA[2] = __builtin_amdgcn_mfma_f32_16x16x32_bf16(cv2, pA.hv, oA[2], 0, 0, 0);
    oB[2] = __builtin_amdgcn_mfma_f32_16x16x32_bf16(cv2, pB.hv, oB[2], 0, 0, 0);
    oA[3] = __builtin_amdgcn_mfma_f32_16x16x32_bf16(cv3, pA.hv, oA[3], 0, 0, 0);
    oB[3] = __builtin_amdgcn_mfma_f32_16x16x32_bf16(cv3, pB.hv, oB[3], 0, 0, 0);

    ck0 = nk0; ck1 = nk1;
    cv0 = nv0; cv1 = nv1; cv2 = nv2; cv3 = nv3;
  }

  float ltA = lAs + __shfl_xor(lAs, 16);
  ltA += __shfl_xor(ltA, 32);
  float ltB = lBs + __shfl_xor(lBs, 16);
  ltB += __shfl_xor(ltB, 32);
  const float invA = 1.f / ltA, invB = 1.f / ltB;

  unsigned short* pAo = ao + ((size_t)(b * NSEQ + q0)) * CDIM + h * 64 + kg * 4;
  unsigned short* pBo = ao + ((size_t)(b * NSEQ + q1)) * CDIM + h * 64 + kg * 4;
#pragma unroll
  for (int dt = 0; dt < 4; ++dt) {
    uint2 ua, ub;
    ua.x = pack2(oA[dt][0] * invA, oA[dt][1] * invA);
    ua.y = pack2(oA[dt][2] * invA, oA[dt][3] * invA);
    ub.x = pack2(oB[dt][0] * invB, oB[dt][1] * invB);
    ub.y = pack2(oB[dt][2] * invB, oB[dt][3] * invB);
    *(uint2*)(pAo + dt * 16) = ua;
    *(uint2*)(pBo + dt * 16) = ub;
  }
}

// ---------------- launch ----------------
extern "C" void kernel_launch(void* const* d_in, const int* in_sizes, int n_in,
                              void* d_out, int out_size, void* d_ws,
                              size_t ws_size, hipStream_t stream) {
  (void)in_sizes; (void)n_in; (void)out_size; (void)ws_size;
  const float* x   = (const float*)d_in[0];
  const float* Wq1 = (const float*)d_in[1];
  const float* Wk1 = (const float*)d_in[2];
  const float* Wq2 = (const float*)d_in[3];
  const float* Wk2 = (const float*)d_in[4];
  const float* Wv  = (const float*)d_in[5];
  const float* Wo  = (const float*)d_in[6];
  const float* bo  = (const float*)d_in[7];
  float* out = (float*)d_out;

  char* ws = (char*)d_ws;
  unsigned short* xb   = (unsigned short*)(ws);              // 8 MB (reused as ao)
  unsigned short* Wall = (unsigned short*)(ws + 8388608);    // 2,883,584 B
  unsigned short* Wob  = (unsigned short*)(ws + 11272192);   // 2 MB
  unsigned short* proj = (unsigned short*)(ws + 13369344);   // 11,534,336 B
  unsigned short* qf   = (unsigned short*)(ws + 24903680);   // 4 MB
  unsigned short* kf   = (unsigned short*)(ws + 29097984);   // 4 MB
  unsigned short* vt   = (unsigned short*)(ws + 33292288);   // 8 MB
  unsigned short* ao   = xb;  // xb dead after proj GEMM

  auto cvt = [&](const float* s, unsigned short* d, int nelem) {
    const int nv = nelem >> 2;
    cvt_kernel<<<dim3((nv + 255) / 256), dim3(256), 0, stream>>>(s, d, nv);
  };
  cvt(x, xb, MROWS * CDIM);
  cvt(Wq1, Wall + 0,      64 * 1024);
  cvt(Wk1, Wall + 65536,  64 * 1024);
  cvt(Wq2, Wall + 131072, 128 * 1024);
  cvt(Wk2, Wall + 262144, 128 * 1024);
  cvt(Wv,  Wall + 393216, 1024 * 1024);
  cvt(Wo,  Wob,           1024 * 1024);

  gemm_bt<0><<<dim3(NPROJ / 128, MROWS / 128), dim3(256), 0, stream>>>(
      xb, Wall, proj, (float*)nullptr, (const float*)nullptr, MROWS, NPROJ, CDIM);

  kron_kernel<<<dim3(BATCH * HHEADS, NSEQ / 256), dim3(256), 0, stream>>>(proj, qf, kf);
  vtrans_kernel<<<dim3(NSEQ / 64, BATCH * HHEADS), dim3(256), 0, stream>>>(proj, vt);

  attn_mfma<<<dim3(NSEQ / 32, BATCH * HHEADS), dim3(64), 0, stream>>>(qf, kf, vt, ao);

  gemm_bt<1><<<dim3(CDIM / 128, MROWS / 128), dim3(256), 0, stream>>>(
      ao, Wob, (unsigned short*)nullptr, out, bo, MROWS, CDIM, CDIM);
}

// Round 5
// 158.542 us; speedup vs baseline: 9.2902x; 1.0862x over previous
//
#include <hip/hip_runtime.h>

// ---------------- problem constants ----------------
#define HHEADS 16
#define R1 4
#define R2 8
#define HD 64
#define CDIM 1024
#define NSEQ 2048
#define BATCH 2
#define NPROJ 1408            // 64 q1 + 64 k1 + 128 q2 + 128 k2 + 1024 v
#define MROWS (BATCH * NSEQ)  // 4096
#define SCALE 0.17677669529663687f   // (R1*R2)^-0.5
#define SCALE_LOG2E 0.2550348612f    // SCALE * log2(e): scores in log2 domain

typedef __attribute__((ext_vector_type(8))) short bf16x8;
typedef __attribute__((ext_vector_type(4))) float f32x4;
typedef __attribute__((ext_vector_type(4))) unsigned int u32x4;

// ---------------- bf16 helpers (raw ushort representation) ----------------
__device__ __forceinline__ float bflo(unsigned u) { return __uint_as_float(u << 16); }
__device__ __forceinline__ float bfhi(unsigned u) { return __uint_as_float(u & 0xffff0000u); }
__device__ __forceinline__ unsigned short f2bfr(float f) {
  unsigned u = __float_as_uint(f);
  u += 0x7fffu + ((u >> 16) & 1u);
  return (unsigned short)(u >> 16);
}
__device__ __forceinline__ unsigned pack2(float a, float b) {
  return (unsigned)f2bfr(a) | ((unsigned)f2bfr(b) << 16);
}
// hardware packed f32x2 -> bf16x2 (RNE), single instruction (T12 recipe)
__device__ __forceinline__ unsigned cvtpk(float a, float b) {
  unsigned r;
  asm("v_cvt_pk_bf16_f32 %0, %1, %2" : "=v"(r) : "v"(a), "v"(b));
  return r;
}
// raw v_exp_f32 = 2^x (scores are kept in log2 domain)
__device__ __forceinline__ float exp2fast(float x) {
#if __has_builtin(__builtin_amdgcn_exp2f)
  return __builtin_amdgcn_exp2f(x);
#else
  float r;
  asm("v_exp_f32 %0, %1" : "=v"(r) : "v"(x));
  return r;
#endif
}

// ---------------- f32 -> bf16 conversion (vectorized) ----------------
__global__ void cvt_kernel(const float* __restrict__ src,
                           unsigned short* __restrict__ dst, int nvec) {
  for (int i = blockIdx.x * blockDim.x + threadIdx.x; i < nvec;
       i += gridDim.x * blockDim.x) {
    const float4 v = ((const float4*)src)[i];
    ushort4 o;
    o.x = f2bfr(v.x);
    o.y = f2bfr(v.y);
    o.z = f2bfr(v.z);
    o.w = f2bfr(v.w);
    ((ushort4*)dst)[i] = o;
  }
}

// ---------------- async global->LDS (16B per lane) ----------------
__device__ __forceinline__ void gld_lds16(const void* g, void* l) {
  __builtin_amdgcn_global_load_lds(
      (const __attribute__((address_space(1))) void*)g,
      (__attribute__((address_space(3))) void*)l, 16, 0, 0);
}

// ---------------- bf16 GEMM: C[M][N] = A[M][K] * Bw[N][K]^T ----------------
template <int OUTMODE>
__global__ __launch_bounds__(256) void gemm_bt(
    const unsigned short* __restrict__ A, const unsigned short* __restrict__ Bw,
    unsigned short* __restrict__ Cb, float* __restrict__ Cf,
    const float* __restrict__ bias, int M, int N, int K) {
  __shared__ unsigned short As[128 * 32];
  __shared__ unsigned short Bs[128 * 32];
  const int tid = threadIdx.x;
  const long brow = (long)blockIdx.y * 128;
  const long bcol = (long)blockIdx.x * 128;
  const int w = tid >> 6, lane = tid & 63;
  const int wr = w >> 1, wc = w & 1;
  const int lr = lane & 15, kg = lane >> 4;

  f32x4 acc[4][4];
#pragma unroll
  for (int m = 0; m < 4; ++m)
#pragma unroll
    for (int n = 0; n < 4; ++n) acc[m][n] = (f32x4){0.f, 0.f, 0.f, 0.f};

  const int off0 = tid * 16;
  const int row0 = off0 >> 6;
  const int kel0 = (off0 & 63) >> 1;

  const int nk = K >> 5;
  for (int kt = 0; kt < nk; ++kt) {
    const long kbase = (long)kt * 32 + kel0;
    gld_lds16(A + (brow + row0) * K + kbase, (char*)As + off0);
    gld_lds16(A + (brow + 64 + row0) * K + kbase, (char*)As + 4096 + off0);
    gld_lds16(Bw + (bcol + row0) * K + kbase, (char*)Bs + off0);
    gld_lds16(Bw + (bcol + 64 + row0) * K + kbase, (char*)Bs + 4096 + off0);
    __syncthreads();

    bf16x8 af[4], bfg[4];
#pragma unroll
    for (int m = 0; m < 4; ++m)
      af[m] = *(const bf16x8*)(As + (wr * 64 + m * 16 + lr) * 32 + kg * 8);
#pragma unroll
    for (int n = 0; n < 4; ++n)
      bfg[n] = *(const bf16x8*)(Bs + (wc * 64 + n * 16 + lr) * 32 + kg * 8);
#pragma unroll
    for (int m = 0; m < 4; ++m)
#pragma unroll
      for (int n = 0; n < 4; ++n)
        acc[m][n] = __builtin_amdgcn_mfma_f32_16x16x32_bf16(af[m], bfg[n],
                                                            acc[m][n], 0, 0, 0);
    __syncthreads();
  }

#pragma unroll
  for (int m = 0; m < 4; ++m) {
#pragma unroll
    for (int i = 0; i < 4; ++i) {
      const long r = brow + wr * 64 + m * 16 + kg * 4 + i;
#pragma unroll
      for (int n = 0; n < 4; ++n) {
        const long c = bcol + wc * 64 + n * 16 + lr;
        const float v = acc[m][n][i];
        if (OUTMODE == 1) {
          Cf[r * N + c] = v + bias[c];
        } else {
          Cb[r * N + c] = f2bfr(v);
        }
      }
    }
  }
}

// ---------------- kron feature build: qf/kf[bh][n][32] -------------------
// qf[r1*8+r2] = q1[r1]*q2[r2]*SCALE*log2e ; kf[r1*8+r2] = k1[r1]*k2[r2]
// Scores come out of the MFMA already in log2 domain -> softmax uses raw
// v_exp_f32 (exp2), no multiply.
__global__ __launch_bounds__(256) void kron_kernel(
    const unsigned short* __restrict__ proj, unsigned short* __restrict__ qf,
    unsigned short* __restrict__ kf) {
  const int bh = blockIdx.x, b = bh >> 4, h = bh & 15;
  const int n = blockIdx.y * 256 + threadIdx.x;
  const unsigned short* row = proj + ((size_t)(b * NSEQ + n)) * NPROJ;
  float q1v[4], k1v[4], q2v[8], k2v[8];
  {
    const uint2 a = *(const uint2*)(row + h * 4);
    q1v[0] = bflo(a.x); q1v[1] = bfhi(a.x); q1v[2] = bflo(a.y); q1v[3] = bfhi(a.y);
    const uint2 c = *(const uint2*)(row + 64 + h * 4);
    k1v[0] = bflo(c.x); k1v[1] = bfhi(c.x); k1v[2] = bflo(c.y); k1v[3] = bfhi(c.y);
    const uint4 d = *(const uint4*)(row + 128 + h * 8);
    q2v[0] = bflo(d.x); q2v[1] = bfhi(d.x); q2v[2] = bflo(d.y); q2v[3] = bfhi(d.y);
    q2v[4] = bflo(d.z); q2v[5] = bfhi(d.z); q2v[6] = bflo(d.w); q2v[7] = bfhi(d.w);
    const uint4 e = *(const uint4*)(row + 256 + h * 8);
    k2v[0] = bflo(e.x); k2v[1] = bfhi(e.x); k2v[2] = bflo(e.y); k2v[3] = bfhi(e.y);
    k2v[4] = bflo(e.z); k2v[5] = bfhi(e.z); k2v[6] = bflo(e.w); k2v[7] = bfhi(e.w);
  }
  unsigned short* oq = qf + ((size_t)bh * NSEQ + n) * 32;
  unsigned short* ok = kf + ((size_t)bh * NSEQ + n) * 32;
#pragma unroll
  for (int i = 0; i < 4; ++i) {
    const float qs = q1v[i] * SCALE_LOG2E;
    uint4 uq, uk;
    uq.x = pack2(qs * q2v[0], qs * q2v[1]);
    uq.y = pack2(qs * q2v[2], qs * q2v[3]);
    uq.z = pack2(qs * q2v[4], qs * q2v[5]);
    uq.w = pack2(qs * q2v[6], qs * q2v[7]);
    uk.x = pack2(k1v[i] * k2v[0], k1v[i] * k2v[1]);
    uk.y = pack2(k1v[i] * k2v[2], k1v[i] * k2v[3]);
    uk.z = pack2(k1v[i] * k2v[4], k1v[i] * k2v[5]);
    uk.w = pack2(k1v[i] * k2v[6], k1v[i] * k2v[7]);
    *(uint4*)(oq + i * 8) = uq;
    *(uint4*)(ok + i * 8) = uk;
  }
}

// ---------------- V transpose: vt[bh][d][n] = proj[b,n][384+h*64+d] -------
__global__ __launch_bounds__(256) void vtrans_kernel(
    const unsigned short* __restrict__ proj, unsigned short* __restrict__ vt) {
  const int bh = blockIdx.y, b = bh >> 4, h = bh & 15;
  const int n0 = blockIdx.x * 64;
  const int tid = threadIdx.x;
#pragma unroll
  for (int it = 0; it < 2; ++it) {
    const int c = tid + it * 256;
    const int dd = c & 63;
    const int nn = (c >> 6) * 8;
    const unsigned short* src =
        proj + ((size_t)(b * NSEQ + n0 + nn)) * NPROJ + 384 + h * 64 + dd;
    unsigned short tmp[8];
#pragma unroll
    for (int j = 0; j < 8; ++j) tmp[j] = src[(size_t)j * NPROJ];
    uint4 u;
    u.x = (unsigned)tmp[0] | ((unsigned)tmp[1] << 16);
    u.y = (unsigned)tmp[2] | ((unsigned)tmp[3] << 16);
    u.z = (unsigned)tmp[4] | ((unsigned)tmp[5] << 16);
    u.w = (unsigned)tmp[6] | ((unsigned)tmp[7] << 16);
    *(uint4*)(vt + ((size_t)bh * 64 + dd) * NSEQ + n0 + nn) = u;
  }
}

// ---------------- MFMA flash attention, key-split (split-K + LSE merge) ---
// 3072 single-wave items, 32 q rows each:
//  A [0,1024):    qb in [32,63], keys [0,1024)   -> 32 tiles, NO mask, partial 0
//  B [1024,2048): qb 63..32 (heavy 1st), keys [1024, (qb+1)*32) -> 32..1 tiles,
//                 masked last tile, partial 1
//  C [2048,3072): qb 31..0 (heavy 1st), keys [0,(qb+1)*32) -> direct write
// Partials: unnormalized O (bf16) + per-q (m, l) in f32 (log2 domain).
__global__ __launch_bounds__(64) void attn_split(
    const unsigned short* __restrict__ qf, const unsigned short* __restrict__ kf,
    const unsigned short* __restrict__ vt, unsigned short* __restrict__ ao,
    unsigned short* __restrict__ po, float* __restrict__ stats) {
  const int item = blockIdx.x;
  int bh, qb, k_lo, nt, mode, slot;  // mode 0 = direct write, 1 = partial
  if (item < 1024) {
    bh = item >> 5; qb = 32 + (item & 31); k_lo = 0; nt = 32; mode = 1; slot = 0;
  } else if (item < 2048) {
    const int t = item - 1024;
    bh = t >> 5; qb = 63 - (t & 31); k_lo = 1024; nt = qb - 31; mode = 1; slot = 1;
  } else {
    const int t = item - 2048;
    bh = t >> 5; qb = 31 - (t & 31); k_lo = 0; nt = qb + 1; mode = 0; slot = 0;
  }
  const int qbase = qb * 32;
  const bool domask = (k_lo + nt * 32) > qbase;  // false for group A

  const int lane = threadIdx.x;
  const int lr = lane & 15, kg = lane >> 4;
  const int b = bh >> 4, h = bh & 15;
  const int q0 = qbase + lr;
  const int q1 = qbase + 16 + lr;

  const unsigned short* qfh = qf + (size_t)bh * NSEQ * 32;
  const unsigned short* kfh = kf + (size_t)bh * NSEQ * 32 + (size_t)k_lo * 32;
  const unsigned short* vth = vt + (size_t)bh * 64 * NSEQ + k_lo;

  const bf16x8 qA = *(const bf16x8*)(qfh + q0 * 32 + kg * 8);
  const bf16x8 qB = *(const bf16x8*)(qfh + q1 * 32 + kg * 8);
  const int krow = (lr >> 2) * 8 + (lr & 3);  // permuted key row for A-frag
  const int kof0 = krow * 32 + kg * 8;
  const int kof1 = kof0 + 4 * 32;
  const int vof0 = (0 * 16 + lr) * NSEQ + kg * 8;
  const int vof1 = (1 * 16 + lr) * NSEQ + kg * 8;
  const int vof2 = (2 * 16 + lr) * NSEQ + kg * 8;
  const int vof3 = (3 * 16 + lr) * NSEQ + kg * 8;
  const f32x4 zero = (f32x4){0.f, 0.f, 0.f, 0.f};

  f32x4 oA[4], oB[4];
#pragma unroll
  for (int dt = 0; dt < 4; ++dt) { oA[dt] = zero; oB[dt] = zero; }
  float mA = -1e30f, mB = -1e30f, lAs = 0.f, lBs = 0.f;

  // prime the pipeline: tile 0 fragments
  bf16x8 ck0 = *(const bf16x8*)(kfh + kof0);
  bf16x8 ck1 = *(const bf16x8*)(kfh + kof1);
  bf16x8 cv0 = *(const bf16x8*)(vth + vof0);
  bf16x8 cv1 = *(const bf16x8*)(vth + vof1);
  bf16x8 cv2 = *(const bf16x8*)(vth + vof2);
  bf16x8 cv3 = *(const bf16x8*)(vth + vof3);

  for (int kt = 0; kt < nt; ++kt) {
    // ---- issue next tile's loads (clamped; last iter re-loads, harmless)
    const int kn = (kt + 1 < nt ? kt + 1 : nt - 1) * 32;
    const bf16x8 nk0 = *(const bf16x8*)(kfh + kn * 32 + kof0);
    const bf16x8 nk1 = *(const bf16x8*)(kfh + kn * 32 + kof1);
    const bf16x8 nv0 = *(const bf16x8*)(vth + vof0 + kn);
    const bf16x8 nv1 = *(const bf16x8*)(vth + vof1 + kn);
    const bf16x8 nv2 = *(const bf16x8*)(vth + vof2 + kn);
    const bf16x8 nv3 = *(const bf16x8*)(vth + vof3 + kn);

    // ---- scores (log2 domain): s{A,B}0[i] = S[key k_lo+kt*32+kg*8+i][q]
    f32x4 sA0 = __builtin_amdgcn_mfma_f32_16x16x32_bf16(ck0, qA, zero, 0, 0, 0);
    f32x4 sA1 = __builtin_amdgcn_mfma_f32_16x16x32_bf16(ck1, qA, zero, 0, 0, 0);
    f32x4 sB0 = __builtin_amdgcn_mfma_f32_16x16x32_bf16(ck0, qB, zero, 0, 0, 0);
    f32x4 sB1 = __builtin_amdgcn_mfma_f32_16x16x32_bf16(ck1, qB, zero, 0, 0, 0);

    if (domask && kt == nt - 1) {  // diagonal tile: causal mask
      const int kb = k_lo + kt * 32 + kg * 8;
#pragma unroll
      for (int i = 0; i < 4; ++i) {
        if (kb + i > q0) sA0[i] = -1e30f;
        if (kb + 4 + i > q0) sA1[i] = -1e30f;
        if (kb + i > q1) sB0[i] = -1e30f;
        if (kb + 4 + i > q1) sB1[i] = -1e30f;
      }
    }

    // ---- lane-local max check; cross-lane reduce ONLY on growth
    const float mxA = fmaxf(fmaxf(fmaxf(sA0[0], sA0[1]), fmaxf(sA0[2], sA0[3])),
                            fmaxf(fmaxf(sA1[0], sA1[1]), fmaxf(sA1[2], sA1[3])));
    const float mxB = fmaxf(fmaxf(fmaxf(sB0[0], sB0[1]), fmaxf(sB0[2], sB0[3])),
                            fmaxf(fmaxf(sB1[0], sB1[1]), fmaxf(sB1[2], sB1[3])));
    const bool ok = (mxA <= mA + 8.f) && (mxB <= mB + 8.f);
    if (!__all(ok)) {
      float rA = fmaxf(mxA, __shfl_xor(mxA, 16));
      rA = fmaxf(rA, __shfl_xor(rA, 32));
      float rB = fmaxf(mxB, __shfl_xor(mxB, 16));
      rB = fmaxf(rB, __shfl_xor(rB, 32));
      const float nmA = fmaxf(mA, rA), nmB = fmaxf(mB, rB);
      const float cA = exp2fast(mA - nmA), cB = exp2fast(mB - nmB);
      mA = nmA; mB = nmB;
      lAs *= cA; lBs *= cB;
#pragma unroll
      for (int dt = 0; dt < 4; ++dt) {
        oA[dt][0] *= cA; oA[dt][1] *= cA; oA[dt][2] *= cA; oA[dt][3] *= cA;
        oB[dt][0] *= cB; oB[dt][1] *= cB; oB[dt][2] *= cB; oB[dt][3] *= cB;
      }
    }

    const float a0 = exp2fast(sA0[0] - mA), a1 = exp2fast(sA0[1] - mA);
    const float a2 = exp2fast(sA0[2] - mA), a3 = exp2fast(sA0[3] - mA);
    const float a4 = exp2fast(sA1[0] - mA), a5 = exp2fast(sA1[1] - mA);
    const float a6 = exp2fast(sA1[2] - mA), a7 = exp2fast(sA1[3] - mA);
    const float b0 = exp2fast(sB0[0] - mB), b1 = exp2fast(sB0[1] - mB);
    const float b2 = exp2fast(sB0[2] - mB), b3 = exp2fast(sB0[3] - mB);
    const float b4 = exp2fast(sB1[0] - mB), b5 = exp2fast(sB1[1] - mB);
    const float b6 = exp2fast(sB1[2] - mB), b7 = exp2fast(sB1[3] - mB);
    lAs += ((a0 + a1) + (a2 + a3)) + ((a4 + a5) + (a6 + a7));
    lBs += ((b0 + b1) + (b2 + b3)) + ((b4 + b5) + (b6 + b7));

    union { u32x4 u; bf16x8 hv; } pA, pB;
    pA.u = (u32x4){cvtpk(a0, a1), cvtpk(a2, a3), cvtpk(a4, a5), cvtpk(a6, a7)};
    pB.u = (u32x4){cvtpk(b0, b1), cvtpk(b2, b3), cvtpk(b4, b5), cvtpk(b6, b7)};

    oA[0] = __builtin_amdgcn_mfma_f32_16x16x32_bf16(cv0, pA.hv, oA[0], 0, 0, 0);
    oB[0] = __builtin_amdgcn_mfma_f32_16x16x32_bf16(cv0, pB.hv, oB[0], 0, 0, 0);
    oA[1] = __builtin_amdgcn_mfma_f32_16x16x32_bf16(cv1, pA.hv, oA[1], 0, 0, 0);
    oB[1] = __builtin_amdgcn_mfma_f32_16x16x32_bf16(cv1, pB.hv, oB[1], 0, 0, 0);
    oA[2] = __builtin_amdgcn_mfma_f32_16x16x32_bf16(cv2, pA.hv, oA[2], 0, 0, 0);
    oB[2] = __builtin_amdgcn_mfma_f32_16x16x32_bf16(cv2, pB.hv, oB[2], 0, 0, 0);
    oA[3] = __builtin_amdgcn_mfma_f32_16x16x32_bf16(cv3, pA.hv, oA[3], 0, 0, 0);
    oB[3] = __builtin_amdgcn_mfma_f32_16x16x32_bf16(cv3, pB.hv, oB[3], 0, 0, 0);

    ck0 = nk0; ck1 = nk1;
    cv0 = nv0; cv1 = nv1; cv2 = nv2; cv3 = nv3;
  }

  float ltA = lAs + __shfl_xor(lAs, 16);
  ltA += __shfl_xor(ltA, 32);
  float ltB = lBs + __shfl_xor(lBs, 16);
  ltB += __shfl_xor(ltB, 32);

  if (mode == 0) {  // direct normalized write to ao
    const float invA = 1.f / ltA, invB = 1.f / ltB;
    unsigned short* pAo = ao + ((size_t)(b * NSEQ + q0)) * CDIM + h * 64 + kg * 4;
    unsigned short* pBo = ao + ((size_t)(b * NSEQ + q1)) * CDIM + h * 64 + kg * 4;
#pragma unroll
    for (int dt = 0; dt < 4; ++dt) {
      uint2 ua, ub;
      ua.x = pack2(oA[dt][0] * invA, oA[dt][1] * invA);
      ua.y = pack2(oA[dt][2] * invA, oA[dt][3] * invA);
      ub.x = pack2(oB[dt][0] * invB, oB[dt][1] * invB);
      ub.y = pack2(oB[dt][2] * invB, oB[dt][3] * invB);
      *(uint2*)(pAo + dt * 16) = ua;
      *(uint2*)(pBo + dt * 16) = ub;
    }
  } else {  // partial: unnormalized bf16 O + (m, l) stats
    const int blk = bh * 32 + (qb - 32);
    unsigned short* pp = po + (size_t)slot * 2097152 + ((size_t)blk * 32) * 64;
    unsigned short* pAo = pp + lr * 64 + kg * 4;
    unsigned short* pBo = pp + (16 + lr) * 64 + kg * 4;
#pragma unroll
    for (int dt = 0; dt < 4; ++dt) {
      uint2 ua, ub;
      ua.x = pack2(oA[dt][0], oA[dt][1]);
      ua.y = pack2(oA[dt][2], oA[dt][3]);
      ub.x = pack2(oB[dt][0], oB[dt][1]);
      ub.y = pack2(oB[dt][2], oB[dt][3]);
      *(uint2*)(pAo + dt * 16) = ua;
      *(uint2*)(pBo + dt * 16) = ub;
    }
    if (kg == 0) {
      float* st = stats + ((size_t)blk * 2 + slot) * 64;
      st[lr * 2] = mA;
      st[lr * 2 + 1] = ltA;
      st[(16 + lr) * 2] = mB;
      st[(16 + lr) * 2 + 1] = ltB;
    }
  }
}

// ---------------- LSE merge of the two key-chunks (qb 32..63) -------------
__global__ __launch_bounds__(64) void merge_kernel(
    const unsigned short* __restrict__ po, const float* __restrict__ stats,
    unsigned short* __restrict__ ao) {
  const int blk = blockIdx.x;  // bh*32 + (qb-32)
  const int bh = blk >> 5, j = blk & 31;
  const int b = bh >> 4, h = bh & 15;
  const int qb = 32 + j;
  const int lane = threadIdx.x;
  const int q = lane >> 1, dh = (lane & 1) * 32;

  const float* st = stats + (size_t)blk * 2 * 64;
  const float m0 = st[q * 2], l0 = st[q * 2 + 1];
  const float m1 = st[64 + q * 2], l1 = st[64 + q * 2 + 1];
  const float M = fmaxf(m0, m1);
  const float s0 = exp2fast(m0 - M), s1 = exp2fast(m1 - M);
  const float L = l0 * s0 + l1 * s1;
  const float f0 = s0 / L, f1 = s1 / L;

  const unsigned short* p0 = po + ((size_t)blk * 32 + q) * 64 + dh;
  const unsigned short* p1 = p0 + 2097152;
  unsigned short* dst =
      ao + ((size_t)(b * NSEQ + qb * 32 + q)) * CDIM + h * 64 + dh;
#pragma unroll
  for (int t = 0; t < 4; ++t) {
    const uint4 u0 = *(const uint4*)(p0 + t * 8);
    const uint4 u1 = *(const uint4*)(p1 + t * 8);
    uint4 o;
    o.x = pack2(bflo(u0.x) * f0 + bflo(u1.x) * f1,
                bfhi(u0.x) * f0 + bfhi(u1.x) * f1);
    o.y = pack2(bflo(u0.y) * f0 + bflo(u1.y) * f1,
                bfhi(u0.y) * f0 + bfhi(u1.y) * f1);
    o.z = pack2(bflo(u0.z) * f0 + bflo(u1.z) * f1,
                bfhi(u0.z) * f0 + bfhi(u1.z) * f1);
    o.w = pack2(bflo(u0.w) * f0 + bflo(u1.w) * f1,
                bfhi(u0.w) * f0 + bfhi(u1.w) * f1);
    *(uint4*)(dst + t * 8) = o;
  }
}

// ---------------- launch ----------------
extern "C" void kernel_launch(void* const* d_in, const int* in_sizes, int n_in,
                              void* d_out, int out_size, void* d_ws,
                              size_t ws_size, hipStream_t stream) {
  (void)in_sizes; (void)n_in; (void)out_size; (void)ws_size;
  const float* x   = (const float*)d_in[0];
  const float* Wq1 = (const float*)d_in[1];
  const float* Wk1 = (const float*)d_in[2];
  const float* Wq2 = (const float*)d_in[3];
  const float* Wk2 = (const float*)d_in[4];
  const float* Wv  = (const float*)d_in[5];
  const float* Wo  = (const float*)d_in[6];
  const float* bo  = (const float*)d_in[7];
  float* out = (float*)d_out;

  char* ws = (char*)d_ws;
  unsigned short* xb   = (unsigned short*)(ws);              // 8 MB (reused as ao)
  unsigned short* Wall = (unsigned short*)(ws + 8388608);    // 2,883,584 B
  unsigned short* Wob  = (unsigned short*)(ws + 11272192);   // 2 MB
  unsigned short* proj = (unsigned short*)(ws + 13369344);   // 11,534,336 B
  unsigned short* qf   = (unsigned short*)(ws + 24903680);   // 4 MB
  unsigned short* kf   = (unsigned short*)(ws + 29097984);   // 4 MB
  unsigned short* vt   = (unsigned short*)(ws + 33292288);   // 8 MB
  unsigned short* ao   = xb;  // xb dead after proj GEMM
  // partials overlay the proj region (dead after kron+vtrans; stream-ordered)
  unsigned short* po    = proj;                              // 2 x 4 MB
  float*          stats = (float*)(ws + 13369344 + 8388608); // 512 KB

  auto cvt = [&](const float* s, unsigned short* d, int nelem) {
    const int nv = nelem >> 2;
    cvt_kernel<<<dim3((nv + 255) / 256), dim3(256), 0, stream>>>(s, d, nv);
  };
  cvt(x, xb, MROWS * CDIM);
  cvt(Wq1, Wall + 0,      64 * 1024);
  cvt(Wk1, Wall + 65536,  64 * 1024);
  cvt(Wq2, Wall + 131072, 128 * 1024);
  cvt(Wk2, Wall + 262144, 128 * 1024);
  cvt(Wv,  Wall + 393216, 1024 * 1024);
  cvt(Wo,  Wob,           1024 * 1024);

  gemm_bt<0><<<dim3(NPROJ / 128, MROWS / 128), dim3(256), 0, stream>>>(
      xb, Wall, proj, (float*)nullptr, (const float*)nullptr, MROWS, NPROJ, CDIM);

  kron_kernel<<<dim3(BATCH * HHEADS, NSEQ / 256), dim3(256), 0, stream>>>(proj, qf, kf);
  vtrans_kernel<<<dim3(NSEQ / 64, BATCH * HHEADS), dim3(256), 0, stream>>>(proj, vt);

  attn_split<<<dim3(3072), dim3(64), 0, stream>>>(qf, kf, vt, ao, po, stats);
  merge_kernel<<<dim3(1024), dim3(64), 0, stream>>>(po, stats, ao);

  gemm_bt<1><<<dim3(CDIM / 128, MROWS / 128), dim3(256), 0, stream>>>(
      ao, Wob, (unsigned short*)nullptr, out, bo, MROWS, CDIM, CDIM);
}